// Round 10
// baseline (318.130 us; speedup 1.0000x reference)
//
#include <hip/hip_runtime.h>
#include <hip/hip_bf16.h>

#define NEG 0.2f

typedef float f32x4 __attribute__((ext_vector_type(4)));
typedef short bf16x8 __attribute__((ext_vector_type(8)));

struct __align__(8) us4 { unsigned short v[4]; };

__device__ __forceinline__ float b2f(unsigned short u){
  union { unsigned int i; float f; } x; x.i = ((unsigned int)u) << 16; return x.f;
}
// native RNE convert; adjacent pairs fuse into v_cvt_pk_bf16_f32
__device__ __forceinline__ unsigned short f2b(float f){
  __hip_bfloat16 h = __float2bfloat16(f);
  return *reinterpret_cast<unsigned short*>(&h);
}

// ---------------- setup: W-pack + deg-zero + scan-state zero + detect --------
__global__ __launch_bounds__(256) void k_setup(
    const float* __restrict__ W0, unsigned short* __restrict__ Wp0,
    const float* __restrict__ W1, unsigned short* __restrict__ Wp1,
    const int* __restrict__ ei, int* __restrict__ meta,
    int* __restrict__ deg, unsigned long long* __restrict__ pack,
    int N, int npack, int nscan){
  const int bid = blockIdx.x;
  if (bid < npack){
    int t = bid*256 + threadIdx.x;
    const int T0 = 16*4*64;          // W0: KB=4
    const int T1 = 16*8*64;          // W1: KB=8
    const float* W; unsigned short* Wp;
    if (t < T0){ W = W0; Wp = Wp0; }
    else if (t < T0 + T1){ W = W1; Wp = Wp1; t -= T0; }
    else return;
    int lane = t & 63;
    int nb = (t >> 6) & 15;
    int kb = (t >> 6) >> 4;
    int kbase = kb*32 + ((lane>>4)<<3);
    int col = nb*16 + (lane&15);
    #pragma unroll
    for (int j=0;j<8;j++) Wp[(size_t)t*8 + j] = f2b(W[(size_t)(kbase+j)*256 + col]);
  } else {
    int i = (bid - npack)*256 + threadIdx.x;
    if (i < N) deg[i] = 0;
    if (i < nscan) pack[i] = 0ull;
    if (i == 0){
      int o = 0;
      #pragma unroll
      for (int j=1;j<128;j+=2) o |= ei[j];
      meta[0] = (o==0) ? 1 : 0;
    }
  }
}

// ---------------- GEMM body (bf16 MFMA, LDS-staged B), fused asrc/adst ------
template<int K, int CVT>
__device__ __forceinline__ void gemm_body(int bid, const void* __restrict__ Xv,
    const unsigned short* __restrict__ Wp,
    const float* __restrict__ aS, const float* __restrict__ aD,
    unsigned short* __restrict__ Hout,
    float* __restrict__ asrc, float* __restrict__ adst, int N){
  constexpr int KB = K/32;
  __shared__ short sB[2][16*64*8];   // 2 x 16KB
  const int lane = threadIdx.x & 63;
  const int wave = threadIdx.x >> 6;
  const int rowbase = bid*64 + wave*16;
  const int l15 = lane & 15, lhi = lane >> 4;
  const int arow = rowbase + l15;

  bf16x8 aF[KB];
  if (CVT){
    const float* X = (const float*)Xv;
    #pragma unroll
    for (int kb=0; kb<KB; kb++){
      bf16x8 a = {};
      if (arow < N){
        f32x4 v0 = *(const f32x4*)(X + (size_t)arow*K + kb*32 + lhi*8);
        f32x4 v1 = *(const f32x4*)(X + (size_t)arow*K + kb*32 + lhi*8 + 4);
        #pragma unroll
        for (int j=0;j<4;j++){ a[j] = (short)f2b(v0[j]); a[j+4] = (short)f2b(v1[j]); }
      }
      aF[kb] = a;
    }
  } else {
    const unsigned short* X = (const unsigned short*)Xv;
    #pragma unroll
    for (int kb=0; kb<KB; kb++){
      bf16x8 a = {};
      if (arow < N) a = *(const bf16x8*)(X + (size_t)arow*K + kb*32 + lhi*8);
      aF[kb] = a;
    }
  }

  auto stage = [&](int buf, int kb){
    #pragma unroll
    for (int q=0;q<4;q++){
      int nb = wave*4 + q;
      const unsigned short* gsrc = Wp + ((size_t)((kb*16 + nb)*64) + lane)*8;
      __builtin_amdgcn_global_load_lds(
          (const __attribute__((address_space(1))) void*)gsrc,
          (__attribute__((address_space(3))) void*)&sB[buf][(size_t)nb*64*8],
          16, 0, 0);
    }
  };

  f32x4 acc[16] = {};
  stage(0, 0);
  __syncthreads();
  #pragma unroll
  for (int kb=0; kb<KB; kb++){
    const int cur = kb & 1;
    if (kb+1 < KB) stage(cur^1, kb+1);
    #pragma unroll
    for (int nb=0; nb<16; nb++){
      bf16x8 b = *(const bf16x8*)(&sB[cur][((size_t)nb*64 + lane)*8]);
      acc[nb] = __builtin_amdgcn_mfma_f32_16x16x32_bf16(aF[kb], b, acc[nb], 0, 0, 0);
    }
    __syncthreads();
  }

  const int r0 = rowbase + lhi*4;   // D rows: (lane>>4)*4 + r, cols: nb*16 + (lane&15)

  float sp[4][4] = {}; float dp[4][4] = {};
  #pragma unroll
  for (int h=0; h<4; h++){
    #pragma unroll
    for (int q=0; q<4; q++){
      const int nb = h*4 + q;
      float ws = aS[h*64 + q*16 + l15];
      float wd = aD[h*64 + q*16 + l15];
      #pragma unroll
      for (int r=0;r<4;r++){ sp[r][h] += acc[nb][r]*ws; dp[r][h] += acc[nb][r]*wd; }
    }
  }
  #pragma unroll
  for (int m=1;m<16;m<<=1){
    #pragma unroll
    for (int r=0;r<4;r++){
      #pragma unroll
      for (int h=0;h<4;h++){
        sp[r][h] += __shfl_xor(sp[r][h], m);
        dp[r][h] += __shfl_xor(dp[r][h], m);
      }
    }
  }
  if (l15 < 4){
    const int h = l15;
    #pragma unroll
    for (int r=0;r<4;r++){
      int row = r0 + r;
      if (row < N){ asrc[row*4+h] = sp[r][h]; adst[row*4+h] = dp[r][h]; }
    }
  }
  #pragma unroll
  for (int nb=0;nb<16;nb++){
    #pragma unroll
    for (int r=0;r<4;r++){
      int row = r0 + r;
      if (row < N) Hout[(size_t)row*256 + nb*16 + l15] = f2b(acc[nb][r]);
    }
  }
}

// fused: layer-0 GEMM (f32 input, CVT) blocks + degree-histogram blocks (x4 edges/thread)
__global__ __launch_bounds__(256) void k_g128deg(
    const float* __restrict__ x, const unsigned short* __restrict__ Wp0,
    const float* __restrict__ aS, const float* __restrict__ aD,
    unsigned short* __restrict__ hb,
    float* __restrict__ asrc, float* __restrict__ adst, int N,
    const int* __restrict__ ei, const int* __restrict__ meta,
    int* __restrict__ deg, int E, int EP, int ngemm){
  const int bid = blockIdx.x;
  if (bid < ngemm){
    gemm_body<128,1>(bid, x, Wp0, aS, aD, hb, asrc, adst, N);
  } else {
    int base = ((bid - ngemm)*256 + threadIdx.x)*4;
    const int m0 = meta[0];
    #pragma unroll
    for (int j=0;j<4;j++){
      int e = base + j;
      if (e >= EP) break;
      int d;
      if (e < E) d = m0 ? ei[2*(size_t)(E+e)] : ei[E+e];
      else       d = e - E;
      if ((unsigned)d < (unsigned)N) atomicAdd(deg + d, 1);
    }
  }
}

__global__ __launch_bounds__(256) void k_gemm256(const unsigned short* __restrict__ X,
    const unsigned short* __restrict__ Wp,
    const float* __restrict__ aS, const float* __restrict__ aD,
    unsigned short* __restrict__ Hout,
    float* __restrict__ asrc, float* __restrict__ adst, int N){
  gemm_body<256,0>(blockIdx.x, X, Wp, aS, aD, Hout, asrc, adst, N);
}

// ---------------- CSR build: single-kernel decoupled-lookback scan ----------
// pack[b] = (status<<32)|value; status 1=aggregate, 2=inclusive. Device-scope
// atomics (AGENT) for cross-XCD visibility. All blocks co-resident (<=256 CUs).
__global__ __launch_bounds__(256) void k_scanall(const int* __restrict__ deg,
    int* __restrict__ rp, int* __restrict__ cur,
    unsigned long long* __restrict__ pack, int N, int nb){
  __shared__ int s[256];
  __shared__ int sprefix;
  const int bid = blockIdx.x, t = threadIdx.x;
  const int i = bid*256 + t;
  const int v = (i < N) ? deg[i] : 0;
  s[t] = v;
  __syncthreads();
  for (int off=1; off<256; off<<=1){
    int x = (t>=off) ? s[t-off] : 0;
    __syncthreads();
    s[t] += x;
    __syncthreads();
  }
  const int total = s[255];
  if (t == 0){
    __hip_atomic_store(&pack[bid], (1ull<<32) | (unsigned)total,
                       __ATOMIC_RELEASE, __HIP_MEMORY_SCOPE_AGENT);
    long long run = 0;
    int j = bid - 1;
    while (j >= 0){
      unsigned long long p;
      do {
        p = __hip_atomic_load(&pack[j], __ATOMIC_ACQUIRE, __HIP_MEMORY_SCOPE_AGENT);
      } while ((p >> 32) == 0);
      run += (int)(p & 0xffffffffu);
      if ((p >> 32) == 2) break;
      j--;
    }
    __hip_atomic_store(&pack[bid], (2ull<<32) | (unsigned)(run + total),
                       __ATOMIC_RELEASE, __HIP_MEMORY_SCOPE_AGENT);
    sprefix = (int)run;
  }
  __syncthreads();
  const int ex = sprefix + s[t] - v;
  if (i < N){ rp[i] = ex; cur[i] = ex; }
  if (bid == nb-1 && t == 255) rp[N] = sprefix + total;
}

__global__ void k_fill(const int* __restrict__ ei, const int* __restrict__ meta,
                       int* __restrict__ cur, int* __restrict__ csr, int E, int EP, int N){
  int e = blockIdx.x*blockDim.x + threadIdx.x;
  if (e >= EP) return;
  int s, d;
  if (e < E){
    if (meta[0]){ s = ei[2*(size_t)e]; d = ei[2*(size_t)(E+e)]; }
    else        { s = ei[e];           d = ei[E+e]; }
  } else { s = d = e - E; }
  if ((unsigned)d >= (unsigned)N) return;
  int pos = atomicAdd(cur + d, 1);
  csr[pos] = s;
}

// ---------------- per-dst softmax + aggregation (H=4, C=64) ----------------
// One wave per dst; 8-edge batches, then 4, then scalar tail.
// FUSE2=1: fuse the layer-2 projection (K=256 -> 2) and emit H2/asrc2/adst2
// directly (xa never materialized).
template<int FUSE2>
__global__ __launch_bounds__(256) void k_agg(const unsigned short* __restrict__ Hb,
    const float* __restrict__ asrc, const float* __restrict__ adst,
    const int* __restrict__ rp, const int* __restrict__ csr,
    const float* __restrict__ bias, unsigned short* __restrict__ Xout, int N,
    const float* __restrict__ W2, const float* __restrict__ as2,
    const float* __restrict__ ad2,
    float* __restrict__ H2, float* __restrict__ asrc2, float* __restrict__ adst2){
  const int lane = threadIdx.x & 63;
  const int dst = blockIdx.x*4 + (threadIdx.x >> 6);
  if (dst >= N) return;
  const int head = lane >> 4;
  const int c0 = lane*4;
  const float ad = adst[dst*4 + head];
  const int s0 = rp[dst], s1 = rp[dst+1];
  float a0=0.f,a1=0.f,a2=0.f,a3=0.f,den=0.f;
  int e = s0;
  for (; e+8 <= s1; e += 8){
    int i0 = csr[e+0], i1 = csr[e+1], i2 = csr[e+2], i3 = csr[e+3];
    int i4 = csr[e+4], i5 = csr[e+5], i6 = csr[e+6], i7 = csr[e+7];
    float x0 = asrc[(size_t)i0*4 + head];
    float x1 = asrc[(size_t)i1*4 + head];
    float x2 = asrc[(size_t)i2*4 + head];
    float x3 = asrc[(size_t)i3*4 + head];
    float x4 = asrc[(size_t)i4*4 + head];
    float x5 = asrc[(size_t)i5*4 + head];
    float x6 = asrc[(size_t)i6*4 + head];
    float x7 = asrc[(size_t)i7*4 + head];
    us4 h0 = *(const us4*)(Hb + (size_t)i0*256 + c0);
    us4 h1 = *(const us4*)(Hb + (size_t)i1*256 + c0);
    us4 h2 = *(const us4*)(Hb + (size_t)i2*256 + c0);
    us4 h3 = *(const us4*)(Hb + (size_t)i3*256 + c0);
    us4 h4 = *(const us4*)(Hb + (size_t)i4*256 + c0);
    us4 h5 = *(const us4*)(Hb + (size_t)i5*256 + c0);
    us4 h6 = *(const us4*)(Hb + (size_t)i6*256 + c0);
    us4 h7 = *(const us4*)(Hb + (size_t)i7*256 + c0);
    x0 += ad; x0 = x0 > 0.f ? x0 : NEG*x0; float e0 = __expf(x0);
    x1 += ad; x1 = x1 > 0.f ? x1 : NEG*x1; float e1 = __expf(x1);
    x2 += ad; x2 = x2 > 0.f ? x2 : NEG*x2; float e2 = __expf(x2);
    x3 += ad; x3 = x3 > 0.f ? x3 : NEG*x3; float e3 = __expf(x3);
    x4 += ad; x4 = x4 > 0.f ? x4 : NEG*x4; float e4 = __expf(x4);
    x5 += ad; x5 = x5 > 0.f ? x5 : NEG*x5; float e5 = __expf(x5);
    x6 += ad; x6 = x6 > 0.f ? x6 : NEG*x6; float e6 = __expf(x6);
    x7 += ad; x7 = x7 > 0.f ? x7 : NEG*x7; float e7 = __expf(x7);
    den += ((e0+e1)+(e2+e3)) + ((e4+e5)+(e6+e7));
    a0 += e0*b2f(h0.v[0]) + e1*b2f(h1.v[0]) + e2*b2f(h2.v[0]) + e3*b2f(h3.v[0])
        + e4*b2f(h4.v[0]) + e5*b2f(h5.v[0]) + e6*b2f(h6.v[0]) + e7*b2f(h7.v[0]);
    a1 += e0*b2f(h0.v[1]) + e1*b2f(h1.v[1]) + e2*b2f(h2.v[1]) + e3*b2f(h3.v[1])
        + e4*b2f(h4.v[1]) + e5*b2f(h5.v[1]) + e6*b2f(h6.v[1]) + e7*b2f(h7.v[1]);
    a2 += e0*b2f(h0.v[2]) + e1*b2f(h1.v[2]) + e2*b2f(h2.v[2]) + e3*b2f(h3.v[2])
        + e4*b2f(h4.v[2]) + e5*b2f(h5.v[2]) + e6*b2f(h6.v[2]) + e7*b2f(h7.v[2]);
    a3 += e0*b2f(h0.v[3]) + e1*b2f(h1.v[3]) + e2*b2f(h2.v[3]) + e3*b2f(h3.v[3])
        + e4*b2f(h4.v[3]) + e5*b2f(h5.v[3]) + e6*b2f(h6.v[3]) + e7*b2f(h7.v[3]);
  }
  for (; e+4 <= s1; e += 4){
    int i0 = csr[e+0], i1 = csr[e+1], i2 = csr[e+2], i3 = csr[e+3];
    float x0 = asrc[(size_t)i0*4 + head];
    float x1 = asrc[(size_t)i1*4 + head];
    float x2 = asrc[(size_t)i2*4 + head];
    float x3 = asrc[(size_t)i3*4 + head];
    us4 h0 = *(const us4*)(Hb + (size_t)i0*256 + c0);
    us4 h1 = *(const us4*)(Hb + (size_t)i1*256 + c0);
    us4 h2 = *(const us4*)(Hb + (size_t)i2*256 + c0);
    us4 h3 = *(const us4*)(Hb + (size_t)i3*256 + c0);
    x0 += ad; x0 = x0 > 0.f ? x0 : NEG*x0; float e0 = __expf(x0);
    x1 += ad; x1 = x1 > 0.f ? x1 : NEG*x1; float e1 = __expf(x1);
    x2 += ad; x2 = x2 > 0.f ? x2 : NEG*x2; float e2 = __expf(x2);
    x3 += ad; x3 = x3 > 0.f ? x3 : NEG*x3; float e3 = __expf(x3);
    den += (e0 + e1) + (e2 + e3);
    a0 += e0*b2f(h0.v[0]) + e1*b2f(h1.v[0]) + e2*b2f(h2.v[0]) + e3*b2f(h3.v[0]);
    a1 += e0*b2f(h0.v[1]) + e1*b2f(h1.v[1]) + e2*b2f(h2.v[1]) + e3*b2f(h3.v[1]);
    a2 += e0*b2f(h0.v[2]) + e1*b2f(h1.v[2]) + e2*b2f(h2.v[2]) + e3*b2f(h3.v[2]);
    a3 += e0*b2f(h0.v[3]) + e1*b2f(h1.v[3]) + e2*b2f(h2.v[3]) + e3*b2f(h3.v[3]);
  }
  for (; e < s1; e++){
    int src = csr[e];
    float al = asrc[(size_t)src*4 + head] + ad;
    al = al > 0.f ? al : NEG*al;
    float ee = __expf(al);
    den += ee;
    us4 hv = *(const us4*)(Hb + (size_t)src*256 + c0);
    a0 += ee * b2f(hv.v[0]);
    a1 += ee * b2f(hv.v[1]);
    a2 += ee * b2f(hv.v[2]);
    a3 += ee * b2f(hv.v[3]);
  }
  float rd = 1.0f/den;
  f32x4 bv = *(const f32x4*)(bias + c0);
  float o0 = tanhf(a0*rd + bv[0]);
  float o1 = tanhf(a1*rd + bv[1]);
  float o2 = tanhf(a2*rd + bv[2]);
  float o3 = tanhf(a3*rd + bv[3]);
  if (FUSE2){
    // layer-2 projection: W2 is [256][2]; lane owns channels c0..c0+3
    f32x4 w01 = *(const f32x4*)(W2 + c0*2);
    f32x4 w23 = *(const f32x4*)(W2 + c0*2 + 4);
    float p0 = o0*w01[0] + o1*w01[2] + o2*w23[0] + o3*w23[2];
    float p1 = o0*w01[1] + o1*w01[3] + o2*w23[1] + o3*w23[3];
    #pragma unroll
    for (int m=1;m<64;m<<=1){ p0 += __shfl_xor(p0,m); p1 += __shfl_xor(p1,m); }
    if (lane == 0){
      H2[(size_t)dst*2+0] = p0;
      H2[(size_t)dst*2+1] = p1;
      asrc2[dst] = p0*as2[0] + p1*as2[1];
      adst2[dst] = p0*ad2[0] + p1*ad2[1];
    }
  } else {
    us4 o;
    o.v[0] = f2b(o0); o.v[1] = f2b(o1); o.v[2] = f2b(o2); o.v[3] = f2b(o3);
    *(us4*)(Xout + (size_t)dst*256 + c0) = o;
  }
}

// 16 lanes per dst (4 dst per wave, 16 dst per block)
__global__ __launch_bounds__(256) void k_agg2(const float* __restrict__ H2,
    const float* __restrict__ asrc2, const float* __restrict__ adst2,
    const int* __restrict__ rp, const int* __restrict__ csr, const float* __restrict__ bb,
    float* __restrict__ out, int N){
  const int sub = threadIdx.x & 15;
  const int dst = blockIdx.x*16 + (threadIdx.x >> 4);
  if (dst >= N) return;
  const float ad = adst2[dst];
  const int s0 = rp[dst], s1 = rp[dst+1];
  float n0=0.f, n1=0.f, den=0.f;
  for (int e=s0+sub; e<s1; e+=16){
    int src = csr[e];
    float al = asrc2[src] + ad;
    al = al>0.f ? al : NEG*al;
    float ee = __expf(al);
    den += ee;
    n0 += ee * H2[src*2+0];
    n1 += ee * H2[src*2+1];
  }
  #pragma unroll
  for (int m=1;m<16;m<<=1){
    n0 += __shfl_xor(n0,m); n1 += __shfl_xor(n1,m); den += __shfl_xor(den,m);
  }
  if (sub==0){
    float o0 = n0/den + bb[0];
    float o1 = n1/den + bb[1];
    float mx = fmaxf(o0,o1);
    float e0 = __expf(o0-mx), e1 = __expf(o1-mx);
    float is = 1.0f/(e0+e1);
    out[(size_t)dst*2+0] = e0*is;
    out[(size_t)dst*2+1] = e1*is;
    out[(size_t)2*N + dst*2+0] = o0;
    out[(size_t)2*N + dst*2+1] = o1;
  }
}

// ---------------- host launcher ----------------
extern "C" void kernel_launch(void* const* d_in, const int* in_sizes, int n_in,
                              void* d_out, int out_size, void* d_ws, size_t ws_size,
                              hipStream_t stream){
  const float* x  = (const float*)d_in[0];
  const int*   ei = (const int*)d_in[1];
  const float* W0 = (const float*)d_in[2];
  const float* as0= (const float*)d_in[3];
  const float* ad0= (const float*)d_in[4];
  const float* b0 = (const float*)d_in[5];
  const float* W1 = (const float*)d_in[6];
  const float* as1= (const float*)d_in[7];
  const float* ad1= (const float*)d_in[8];
  const float* b1 = (const float*)d_in[9];
  const float* W2 = (const float*)d_in[10];
  const float* as2= (const float*)d_in[11];
  const float* ad2= (const float*)d_in[12];
  const float* b2 = (const float*)d_in[13];

  const int N  = in_sizes[0] / 128;
  const int E  = in_sizes[1] / 2;
  const int EP = E + N;
  float* outp = (float*)d_out;

  char* w = (char*)d_ws;
  size_t off = 0;
  auto alloc = [&](size_t bytes)->char*{
    char* p = w + off; off = (off + bytes + 255) & ~(size_t)255; return p;
  };
  unsigned short* hb  = (unsigned short*)alloc((size_t)N*256*2);  // [N][256]
  unsigned short* xa  = (unsigned short*)alloc((size_t)N*256*2);  // [N][256]
  float* asrc  = (float*)alloc((size_t)N*4*4);   // [N][4]
  float* adst  = (float*)alloc((size_t)N*4*4);   // [N][4]
  float* asrc2 = (float*)alloc((size_t)N*4);
  float* adst2 = (float*)alloc((size_t)N*4);
  float* H2    = (float*)alloc((size_t)N*2*4);
  unsigned short* Wp0 = (unsigned short*)alloc((size_t)128*256*2);
  unsigned short* Wp1 = (unsigned short*)alloc((size_t)256*256*2);
  int* deg   = (int*)alloc((size_t)N*4);
  int* rp    = (int*)alloc((size_t)(N+1)*4);
  int* cur   = (int*)alloc((size_t)N*4);
  unsigned long long* pack = (unsigned long long*)alloc(512*8);
  int* meta  = (int*)alloc(8*4);
  int* csr   = (int*)alloc((size_t)EP*4);
  (void)ws_size; (void)n_in; (void)out_size;

  const int npack = (16*4*64 + 16*8*64) / 256;          // 48
  const int ninit = (N + 255)/256;
  const int nb1 = (N + 255)/256;                        // scan blocks
  k_setup<<<npack + ninit, 256, 0, stream>>>(W0, Wp0, W1, Wp1, ei, meta, deg, pack,
                                             N, npack, nb1);

  const int ngemm = (N + 63)/64;
  const int ndeg  = (EP + 1023)/1024;
  // layer-0 GEMM runs concurrently with the degree histogram
  k_g128deg<<<ngemm + ndeg, 256, 0, stream>>>(x, Wp0, as0, ad0, hb, asrc, adst, N,
                                              ei, meta, deg, E, EP, ngemm);

  // single-kernel decoupled-lookback prefix scan
  k_scanall<<<nb1, 256, 0, stream>>>(deg, rp, cur, pack, N, nb1);
  k_fill   <<<(EP + 255)/256, 256, 0, stream>>>(ei, meta, cur, csr, E, EP, N);

  // layer 0 aggregation -> xa
  k_agg<0><<<(N + 3)/4, 256, 0, stream>>>(hb, asrc, adst, rp, csr, b0, xa, N,
                                          nullptr, nullptr, nullptr, nullptr, nullptr, nullptr);
  // layer 1: xa -> h1
  k_gemm256<<<ngemm, 256, 0, stream>>>(xa, Wp1, as1, ad1, hb, asrc, adst, N);
  // layer-1 aggregation with fused layer-2 projection -> H2, asrc2, adst2
  k_agg<1><<<(N + 3)/4, 256, 0, stream>>>(hb, asrc, adst, rp, csr, b1, nullptr, N,
                                          W2, as2, ad2, H2, asrc2, adst2);
  // layer 2 aggregation + softmax -> out
  k_agg2  <<<(N + 15)/16, 256, 0, stream>>>(H2, asrc2, adst2, rp, csr, b2, outp, N);
}

// Round 11
// 277.181 us; speedup vs baseline: 1.1477x; 1.1477x over previous
//
#include <hip/hip_runtime.h>
#include <hip/hip_bf16.h>

#define NEG 0.2f

typedef float f32x4 __attribute__((ext_vector_type(4)));
typedef short bf16x8 __attribute__((ext_vector_type(8)));

struct __align__(8) us4 { unsigned short v[4]; };

__device__ __forceinline__ float b2f(unsigned short u){
  union { unsigned int i; float f; } x; x.i = ((unsigned int)u) << 16; return x.f;
}
// native RNE convert; adjacent pairs fuse into v_cvt_pk_bf16_f32
__device__ __forceinline__ unsigned short f2b(float f){
  __hip_bfloat16 h = __float2bfloat16(f);
  return *reinterpret_cast<unsigned short*>(&h);
}

// ---------------- setup: W-pack + deg-zero + int64 detect (multi-role) -------
__global__ __launch_bounds__(256) void k_setup(
    const float* __restrict__ W0, unsigned short* __restrict__ Wp0,
    const float* __restrict__ W1, unsigned short* __restrict__ Wp1,
    const int* __restrict__ ei, int* __restrict__ meta,
    int* __restrict__ deg, int N, int npack){
  const int bid = blockIdx.x;
  if (bid < npack){
    int t = bid*256 + threadIdx.x;
    const int T0 = 16*4*64;          // W0: KB=4
    const int T1 = 16*8*64;          // W1: KB=8
    const float* W; unsigned short* Wp;
    if (t < T0){ W = W0; Wp = Wp0; }
    else if (t < T0 + T1){ W = W1; Wp = Wp1; t -= T0; }
    else return;
    int lane = t & 63;
    int nb = (t >> 6) & 15;
    int kb = (t >> 6) >> 4;
    int kbase = kb*32 + ((lane>>4)<<3);
    int col = nb*16 + (lane&15);
    #pragma unroll
    for (int j=0;j<8;j++) Wp[(size_t)t*8 + j] = f2b(W[(size_t)(kbase+j)*256 + col]);
  } else {
    int i = (bid - npack)*256 + threadIdx.x;
    if (i < N) deg[i] = 0;
    if (i == 0){
      int o = 0;
      #pragma unroll
      for (int j=1;j<128;j+=2) o |= ei[j];
      meta[0] = (o==0) ? 1 : 0;
    }
  }
}

// ---------------- GEMM body (bf16 MFMA, LDS-staged B), fused asrc/adst ------
template<int K, int CVT>
__device__ __forceinline__ void gemm_body(int bid, const void* __restrict__ Xv,
    const unsigned short* __restrict__ Wp,
    const float* __restrict__ aS, const float* __restrict__ aD,
    unsigned short* __restrict__ Hout,
    float* __restrict__ asrc, float* __restrict__ adst, int N){
  constexpr int KB = K/32;
  __shared__ short sB[2][16*64*8];   // 2 x 16KB
  const int lane = threadIdx.x & 63;
  const int wave = threadIdx.x >> 6;
  const int rowbase = bid*64 + wave*16;
  const int l15 = lane & 15, lhi = lane >> 4;
  const int arow = rowbase + l15;

  bf16x8 aF[KB];
  if (CVT){
    const float* X = (const float*)Xv;
    #pragma unroll
    for (int kb=0; kb<KB; kb++){
      bf16x8 a = {};
      if (arow < N){
        f32x4 v0 = *(const f32x4*)(X + (size_t)arow*K + kb*32 + lhi*8);
        f32x4 v1 = *(const f32x4*)(X + (size_t)arow*K + kb*32 + lhi*8 + 4);
        #pragma unroll
        for (int j=0;j<4;j++){ a[j] = (short)f2b(v0[j]); a[j+4] = (short)f2b(v1[j]); }
      }
      aF[kb] = a;
    }
  } else {
    const unsigned short* X = (const unsigned short*)Xv;
    #pragma unroll
    for (int kb=0; kb<KB; kb++){
      bf16x8 a = {};
      if (arow < N) a = *(const bf16x8*)(X + (size_t)arow*K + kb*32 + lhi*8);
      aF[kb] = a;
    }
  }

  auto stage = [&](int buf, int kb){
    #pragma unroll
    for (int q=0;q<4;q++){
      int nb = wave*4 + q;
      const unsigned short* gsrc = Wp + ((size_t)((kb*16 + nb)*64) + lane)*8;
      __builtin_amdgcn_global_load_lds(
          (const __attribute__((address_space(1))) void*)gsrc,
          (__attribute__((address_space(3))) void*)&sB[buf][(size_t)nb*64*8],
          16, 0, 0);
    }
  };

  f32x4 acc[16] = {};
  stage(0, 0);
  __syncthreads();
  #pragma unroll
  for (int kb=0; kb<KB; kb++){
    const int cur = kb & 1;
    if (kb+1 < KB) stage(cur^1, kb+1);
    #pragma unroll
    for (int nb=0; nb<16; nb++){
      bf16x8 b = *(const bf16x8*)(&sB[cur][((size_t)nb*64 + lane)*8]);
      acc[nb] = __builtin_amdgcn_mfma_f32_16x16x32_bf16(aF[kb], b, acc[nb], 0, 0, 0);
    }
    __syncthreads();
  }

  const int r0 = rowbase + lhi*4;   // D rows: (lane>>4)*4 + r, cols: nb*16 + (lane&15)

  float sp[4][4] = {}; float dp[4][4] = {};
  #pragma unroll
  for (int h=0; h<4; h++){
    #pragma unroll
    for (int q=0; q<4; q++){
      const int nb = h*4 + q;
      float ws = aS[h*64 + q*16 + l15];
      float wd = aD[h*64 + q*16 + l15];
      #pragma unroll
      for (int r=0;r<4;r++){ sp[r][h] += acc[nb][r]*ws; dp[r][h] += acc[nb][r]*wd; }
    }
  }
  #pragma unroll
  for (int m=1;m<16;m<<=1){
    #pragma unroll
    for (int r=0;r<4;r++){
      #pragma unroll
      for (int h=0;h<4;h++){
        sp[r][h] += __shfl_xor(sp[r][h], m);
        dp[r][h] += __shfl_xor(dp[r][h], m);
      }
    }
  }
  if (l15 < 4){
    const int h = l15;
    #pragma unroll
    for (int r=0;r<4;r++){
      int row = r0 + r;
      if (row < N){ asrc[row*4+h] = sp[r][h]; adst[row*4+h] = dp[r][h]; }
    }
  }
  #pragma unroll
  for (int nb=0;nb<16;nb++){
    #pragma unroll
    for (int r=0;r<4;r++){
      int row = r0 + r;
      if (row < N) Hout[(size_t)row*256 + nb*16 + l15] = f2b(acc[nb][r]);
    }
  }
}

// fused: layer-0 GEMM (f32 input, CVT) blocks + degree-histogram blocks (x4 edges/thread)
__global__ __launch_bounds__(256) void k_g128deg(
    const float* __restrict__ x, const unsigned short* __restrict__ Wp0,
    const float* __restrict__ aS, const float* __restrict__ aD,
    unsigned short* __restrict__ hb,
    float* __restrict__ asrc, float* __restrict__ adst, int N,
    const int* __restrict__ ei, const int* __restrict__ meta,
    int* __restrict__ deg, int E, int EP, int ngemm){
  const int bid = blockIdx.x;
  if (bid < ngemm){
    gemm_body<128,1>(bid, x, Wp0, aS, aD, hb, asrc, adst, N);
  } else {
    int base = ((bid - ngemm)*256 + threadIdx.x)*4;
    const int m0 = meta[0];
    #pragma unroll
    for (int j=0;j<4;j++){
      int e = base + j;
      if (e >= EP) break;
      int d;
      if (e < E) d = m0 ? ei[2*(size_t)(E+e)] : ei[E+e];
      else       d = e - E;
      if ((unsigned)d < (unsigned)N) atomicAdd(deg + d, 1);
    }
  }
}

__global__ __launch_bounds__(256) void k_gemm256(const unsigned short* __restrict__ X,
    const unsigned short* __restrict__ Wp,
    const float* __restrict__ aS, const float* __restrict__ aD,
    unsigned short* __restrict__ Hout,
    float* __restrict__ asrc, float* __restrict__ adst, int N){
  gemm_body<256,0>(blockIdx.x, X, Wp, aS, aD, Hout, asrc, adst, N);
}

// ---------------- CSR build ----------------

__global__ void k_scan1(const int* __restrict__ deg, int* __restrict__ tmp,
                        int* __restrict__ bsum, int N){
  __shared__ int s[256];
  int t = threadIdx.x;
  int i = blockIdx.x*256 + t;
  int v = (i < N) ? deg[i] : 0;
  s[t] = v;
  __syncthreads();
  for (int off=1; off<256; off<<=1){
    int x = (t>=off) ? s[t-off] : 0;
    __syncthreads();
    s[t] += x;
    __syncthreads();
  }
  if (i < N) tmp[i] = s[t] - v;
  if (t == 255) bsum[blockIdx.x] = s[255];
}

__global__ void k_scan2(const int* __restrict__ bsum, int* __restrict__ bsumx,
                        int* __restrict__ meta, int n){
  __shared__ int s[256];
  int t = threadIdx.x;
  int v = (t < n) ? bsum[t] : 0;
  s[t] = v;
  __syncthreads();
  for (int off=1; off<256; off<<=1){
    int x = (t>=off) ? s[t-off] : 0;
    __syncthreads();
    s[t] += x;
    __syncthreads();
  }
  bsumx[t] = s[t] - v;
  if (t == 255) meta[1] = s[255];
}

__global__ void k_scan3(const int* __restrict__ tmp, const int* __restrict__ bsumx,
                        const int* __restrict__ meta,
                        int* __restrict__ rp, int* __restrict__ cur, int N){
  int i = blockIdx.x*256 + threadIdx.x;
  if (i < N){ int v = tmp[i] + bsumx[i>>8]; rp[i] = v; cur[i] = v; }
  if (i == 0) rp[N] = meta[1];
}

__global__ void k_fill(const int* __restrict__ ei, const int* __restrict__ meta,
                       int* __restrict__ cur, int* __restrict__ csr, int E, int EP, int N){
  int e = blockIdx.x*blockDim.x + threadIdx.x;
  if (e >= EP) return;
  int s, d;
  if (e < E){
    if (meta[0]){ s = ei[2*(size_t)e]; d = ei[2*(size_t)(E+e)]; }
    else        { s = ei[e];           d = ei[E+e]; }
  } else { s = d = e - E; }
  if ((unsigned)d >= (unsigned)N) return;
  int pos = atomicAdd(cur + d, 1);
  csr[pos] = s;
}

// ---------------- per-dst softmax + aggregation (H=4, C=64) ----------------
// One wave per dst; 8-edge batches, then 4, then scalar tail.
// FUSE2=1: fuse the layer-2 projection (K=256 -> 2) and emit H2/asrc2/adst2
// directly (xa never materialized).
template<int FUSE2>
__global__ __launch_bounds__(256) void k_agg(const unsigned short* __restrict__ Hb,
    const float* __restrict__ asrc, const float* __restrict__ adst,
    const int* __restrict__ rp, const int* __restrict__ csr,
    const float* __restrict__ bias, unsigned short* __restrict__ Xout, int N,
    const float* __restrict__ W2, const float* __restrict__ as2,
    const float* __restrict__ ad2,
    float* __restrict__ H2, float* __restrict__ asrc2, float* __restrict__ adst2){
  const int lane = threadIdx.x & 63;
  const int dst = blockIdx.x*4 + (threadIdx.x >> 6);
  if (dst >= N) return;
  const int head = lane >> 4;
  const int c0 = lane*4;
  const float ad = adst[dst*4 + head];
  const int s0 = rp[dst], s1 = rp[dst+1];
  float a0=0.f,a1=0.f,a2=0.f,a3=0.f,den=0.f;
  int e = s0;
  for (; e+8 <= s1; e += 8){
    int i0 = csr[e+0], i1 = csr[e+1], i2 = csr[e+2], i3 = csr[e+3];
    int i4 = csr[e+4], i5 = csr[e+5], i6 = csr[e+6], i7 = csr[e+7];
    float x0 = asrc[(size_t)i0*4 + head];
    float x1 = asrc[(size_t)i1*4 + head];
    float x2 = asrc[(size_t)i2*4 + head];
    float x3 = asrc[(size_t)i3*4 + head];
    float x4 = asrc[(size_t)i4*4 + head];
    float x5 = asrc[(size_t)i5*4 + head];
    float x6 = asrc[(size_t)i6*4 + head];
    float x7 = asrc[(size_t)i7*4 + head];
    us4 h0 = *(const us4*)(Hb + (size_t)i0*256 + c0);
    us4 h1 = *(const us4*)(Hb + (size_t)i1*256 + c0);
    us4 h2 = *(const us4*)(Hb + (size_t)i2*256 + c0);
    us4 h3 = *(const us4*)(Hb + (size_t)i3*256 + c0);
    us4 h4 = *(const us4*)(Hb + (size_t)i4*256 + c0);
    us4 h5 = *(const us4*)(Hb + (size_t)i5*256 + c0);
    us4 h6 = *(const us4*)(Hb + (size_t)i6*256 + c0);
    us4 h7 = *(const us4*)(Hb + (size_t)i7*256 + c0);
    x0 += ad; x0 = x0 > 0.f ? x0 : NEG*x0; float e0 = __expf(x0);
    x1 += ad; x1 = x1 > 0.f ? x1 : NEG*x1; float e1 = __expf(x1);
    x2 += ad; x2 = x2 > 0.f ? x2 : NEG*x2; float e2 = __expf(x2);
    x3 += ad; x3 = x3 > 0.f ? x3 : NEG*x3; float e3 = __expf(x3);
    x4 += ad; x4 = x4 > 0.f ? x4 : NEG*x4; float e4 = __expf(x4);
    x5 += ad; x5 = x5 > 0.f ? x5 : NEG*x5; float e5 = __expf(x5);
    x6 += ad; x6 = x6 > 0.f ? x6 : NEG*x6; float e6 = __expf(x6);
    x7 += ad; x7 = x7 > 0.f ? x7 : NEG*x7; float e7 = __expf(x7);
    den += ((e0+e1)+(e2+e3)) + ((e4+e5)+(e6+e7));
    a0 += e0*b2f(h0.v[0]) + e1*b2f(h1.v[0]) + e2*b2f(h2.v[0]) + e3*b2f(h3.v[0])
        + e4*b2f(h4.v[0]) + e5*b2f(h5.v[0]) + e6*b2f(h6.v[0]) + e7*b2f(h7.v[0]);
    a1 += e0*b2f(h0.v[1]) + e1*b2f(h1.v[1]) + e2*b2f(h2.v[1]) + e3*b2f(h3.v[1])
        + e4*b2f(h4.v[1]) + e5*b2f(h5.v[1]) + e6*b2f(h6.v[1]) + e7*b2f(h7.v[1]);
    a2 += e0*b2f(h0.v[2]) + e1*b2f(h1.v[2]) + e2*b2f(h2.v[2]) + e3*b2f(h3.v[2])
        + e4*b2f(h4.v[2]) + e5*b2f(h5.v[2]) + e6*b2f(h6.v[2]) + e7*b2f(h7.v[2]);
    a3 += e0*b2f(h0.v[3]) + e1*b2f(h1.v[3]) + e2*b2f(h2.v[3]) + e3*b2f(h3.v[3])
        + e4*b2f(h4.v[3]) + e5*b2f(h5.v[3]) + e6*b2f(h6.v[3]) + e7*b2f(h7.v[3]);
  }
  for (; e+4 <= s1; e += 4){
    int i0 = csr[e+0], i1 = csr[e+1], i2 = csr[e+2], i3 = csr[e+3];
    float x0 = asrc[(size_t)i0*4 + head];
    float x1 = asrc[(size_t)i1*4 + head];
    float x2 = asrc[(size_t)i2*4 + head];
    float x3 = asrc[(size_t)i3*4 + head];
    us4 h0 = *(const us4*)(Hb + (size_t)i0*256 + c0);
    us4 h1 = *(const us4*)(Hb + (size_t)i1*256 + c0);
    us4 h2 = *(const us4*)(Hb + (size_t)i2*256 + c0);
    us4 h3 = *(const us4*)(Hb + (size_t)i3*256 + c0);
    x0 += ad; x0 = x0 > 0.f ? x0 : NEG*x0; float e0 = __expf(x0);
    x1 += ad; x1 = x1 > 0.f ? x1 : NEG*x1; float e1 = __expf(x1);
    x2 += ad; x2 = x2 > 0.f ? x2 : NEG*x2; float e2 = __expf(x2);
    x3 += ad; x3 = x3 > 0.f ? x3 : NEG*x3; float e3 = __expf(x3);
    den += (e0 + e1) + (e2 + e3);
    a0 += e0*b2f(h0.v[0]) + e1*b2f(h1.v[0]) + e2*b2f(h2.v[0]) + e3*b2f(h3.v[0]);
    a1 += e0*b2f(h0.v[1]) + e1*b2f(h1.v[1]) + e2*b2f(h2.v[1]) + e3*b2f(h3.v[1]);
    a2 += e0*b2f(h0.v[2]) + e1*b2f(h1.v[2]) + e2*b2f(h2.v[2]) + e3*b2f(h3.v[2]);
    a3 += e0*b2f(h0.v[3]) + e1*b2f(h1.v[3]) + e2*b2f(h2.v[3]) + e3*b2f(h3.v[3]);
  }
  for (; e < s1; e++){
    int src = csr[e];
    float al = asrc[(size_t)src*4 + head] + ad;
    al = al > 0.f ? al : NEG*al;
    float ee = __expf(al);
    den += ee;
    us4 hv = *(const us4*)(Hb + (size_t)src*256 + c0);
    a0 += ee * b2f(hv.v[0]);
    a1 += ee * b2f(hv.v[1]);
    a2 += ee * b2f(hv.v[2]);
    a3 += ee * b2f(hv.v[3]);
  }
  float rd = 1.0f/den;
  f32x4 bv = *(const f32x4*)(bias + c0);
  float o0 = tanhf(a0*rd + bv[0]);
  float o1 = tanhf(a1*rd + bv[1]);
  float o2 = tanhf(a2*rd + bv[2]);
  float o3 = tanhf(a3*rd + bv[3]);
  if (FUSE2){
    // layer-2 projection: W2 is [256][2]; lane owns channels c0..c0+3
    f32x4 w01 = *(const f32x4*)(W2 + c0*2);
    f32x4 w23 = *(const f32x4*)(W2 + c0*2 + 4);
    float p0 = o0*w01[0] + o1*w01[2] + o2*w23[0] + o3*w23[2];
    float p1 = o0*w01[1] + o1*w01[3] + o2*w23[1] + o3*w23[3];
    #pragma unroll
    for (int m=1;m<64;m<<=1){ p0 += __shfl_xor(p0,m); p1 += __shfl_xor(p1,m); }
    if (lane == 0){
      H2[(size_t)dst*2+0] = p0;
      H2[(size_t)dst*2+1] = p1;
      asrc2[dst] = p0*as2[0] + p1*as2[1];
      adst2[dst] = p0*ad2[0] + p1*ad2[1];
    }
  } else {
    us4 o;
    o.v[0] = f2b(o0); o.v[1] = f2b(o1); o.v[2] = f2b(o2); o.v[3] = f2b(o3);
    *(us4*)(Xout + (size_t)dst*256 + c0) = o;
  }
}

// 16 lanes per dst (4 dst per wave, 16 dst per block)
__global__ __launch_bounds__(256) void k_agg2(const float* __restrict__ H2,
    const float* __restrict__ asrc2, const float* __restrict__ adst2,
    const int* __restrict__ rp, const int* __restrict__ csr, const float* __restrict__ bb,
    float* __restrict__ out, int N){
  const int sub = threadIdx.x & 15;
  const int dst = blockIdx.x*16 + (threadIdx.x >> 4);
  if (dst >= N) return;
  const float ad = adst2[dst];
  const int s0 = rp[dst], s1 = rp[dst+1];
  float n0=0.f, n1=0.f, den=0.f;
  for (int e=s0+sub; e<s1; e+=16){
    int src = csr[e];
    float al = asrc2[src] + ad;
    al = al>0.f ? al : NEG*al;
    float ee = __expf(al);
    den += ee;
    n0 += ee * H2[src*2+0];
    n1 += ee * H2[src*2+1];
  }
  #pragma unroll
  for (int m=1;m<16;m<<=1){
    n0 += __shfl_xor(n0,m); n1 += __shfl_xor(n1,m); den += __shfl_xor(den,m);
  }
  if (sub==0){
    float o0 = n0/den + bb[0];
    float o1 = n1/den + bb[1];
    float mx = fmaxf(o0,o1);
    float e0 = __expf(o0-mx), e1 = __expf(o1-mx);
    float is = 1.0f/(e0+e1);
    out[(size_t)dst*2+0] = e0*is;
    out[(size_t)dst*2+1] = e1*is;
    out[(size_t)2*N + dst*2+0] = o0;
    out[(size_t)2*N + dst*2+1] = o1;
  }
}

// ---------------- host launcher ----------------
extern "C" void kernel_launch(void* const* d_in, const int* in_sizes, int n_in,
                              void* d_out, int out_size, void* d_ws, size_t ws_size,
                              hipStream_t stream){
  const float* x  = (const float*)d_in[0];
  const int*   ei = (const int*)d_in[1];
  const float* W0 = (const float*)d_in[2];
  const float* as0= (const float*)d_in[3];
  const float* ad0= (const float*)d_in[4];
  const float* b0 = (const float*)d_in[5];
  const float* W1 = (const float*)d_in[6];
  const float* as1= (const float*)d_in[7];
  const float* ad1= (const float*)d_in[8];
  const float* b1 = (const float*)d_in[9];
  const float* W2 = (const float*)d_in[10];
  const float* as2= (const float*)d_in[11];
  const float* ad2= (const float*)d_in[12];
  const float* b2 = (const float*)d_in[13];

  const int N  = in_sizes[0] / 128;
  const int E  = in_sizes[1] / 2;
  const int EP = E + N;
  float* outp = (float*)d_out;

  char* w = (char*)d_ws;
  size_t off = 0;
  auto alloc = [&](size_t bytes)->char*{
    char* p = w + off; off = (off + bytes + 255) & ~(size_t)255; return p;
  };
  unsigned short* hb  = (unsigned short*)alloc((size_t)N*256*2);  // [N][256]
  unsigned short* xa  = (unsigned short*)alloc((size_t)N*256*2);  // [N][256]
  float* asrc  = (float*)alloc((size_t)N*4*4);   // [N][4]
  float* adst  = (float*)alloc((size_t)N*4*4);   // [N][4]
  float* asrc2 = (float*)alloc((size_t)N*4);
  float* adst2 = (float*)alloc((size_t)N*4);
  float* H2    = (float*)alloc((size_t)N*2*4);
  unsigned short* Wp0 = (unsigned short*)alloc((size_t)128*256*2);
  unsigned short* Wp1 = (unsigned short*)alloc((size_t)256*256*2);
  int* deg   = (int*)alloc((size_t)N*4);
  int* rp    = (int*)alloc((size_t)(N+1)*4);
  int* cur   = (int*)alloc((size_t)N*4);
  int* tmp   = (int*)alloc((size_t)N*4);
  int* bsum  = (int*)alloc(256*4);
  int* bsumx = (int*)alloc(256*4);
  int* meta  = (int*)alloc(8*4);
  int* csr   = (int*)alloc((size_t)EP*4);
  (void)ws_size; (void)n_in; (void)out_size;

  const int npack = (16*4*64 + 16*8*64) / 256;          // 48
  const int ninit = (N + 255)/256;
  k_setup<<<npack + ninit, 256, 0, stream>>>(W0, Wp0, W1, Wp1, ei, meta, deg, N, npack);

  const int ngemm = (N + 63)/64;
  const int ndeg  = (EP + 1023)/1024;
  // layer-0 GEMM runs concurrently with the degree histogram
  k_g128deg<<<ngemm + ndeg, 256, 0, stream>>>(x, Wp0, as0, ad0, hb, asrc, adst, N,
                                              ei, meta, deg, E, EP, ngemm);

  const int nb1 = (N + 255)/256;
  k_scan1 <<<nb1, 256, 0, stream>>>(deg, tmp, bsum, N);
  k_scan2 <<<1, 256, 0, stream>>>(bsum, bsumx, meta, nb1);
  k_scan3 <<<nb1, 256, 0, stream>>>(tmp, bsumx, meta, rp, cur, N);
  k_fill  <<<(EP + 255)/256, 256, 0, stream>>>(ei, meta, cur, csr, E, EP, N);

  // layer 0 aggregation -> xa
  k_agg<0><<<(N + 3)/4, 256, 0, stream>>>(hb, asrc, adst, rp, csr, b0, xa, N,
                                          nullptr, nullptr, nullptr, nullptr, nullptr, nullptr);
  // layer 1: xa -> h1
  k_gemm256<<<ngemm, 256, 0, stream>>>(xa, Wp1, as1, ad1, hb, asrc, adst, N);
  // layer-1 aggregation with fused layer-2 projection -> H2, asrc2, adst2
  k_agg<1><<<(N + 3)/4, 256, 0, stream>>>(hb, asrc, adst, rp, csr, b1, nullptr, N,
                                          W2, as2, ad2, H2, asrc2, adst2);
  // layer 2 aggregation + softmax -> out
  k_agg2  <<<(N + 15)/16, 256, 0, stream>>>(H2, asrc2, adst2, rp, csr, b2, outp, N);
}